// Round 1
// baseline (1068.263 us; speedup 1.0000x reference)
//
#include <hip/hip_runtime.h>

#define NSEQ 512
#define DCH 128
#define RTOT (NSEQ * NSEQ) /* 262144 */

typedef __attribute__((ext_vector_type(8))) short bf16x8;
typedef __attribute__((ext_vector_type(4))) float f32x4;

__device__ __forceinline__ unsigned short f2bf(float v) {
  union { float f; unsigned int u; } x; x.f = v;
  unsigned int u = x.u;
  return (unsigned short)((u + 0x7fffu + ((u >> 16) & 1u)) >> 16);
}
__device__ __forceinline__ float bf2f(unsigned short s) {
  union { unsigned int u; float f; } x; x.u = ((unsigned int)s) << 16;
  return x.f;
}
__device__ __forceinline__ float sigmoidf(float x) { return 1.f / (1.f + __expf(-x)); }

// ---------------------------------------------------------------------------
// prep: pack weights (reordered) into bf16.
// Wc rows: [0,128)=W_fg rows 0..127 (to-feat), [128,256)=W_fg rows 256..383
// (to-gate), [256,384)=W_fg rows 128..255 (from-feat), [384,512)=W_fg rows
// 384..511 (from-gate), [512,640)=W_go.  bc: same row order, fp32.
// ---------------------------------------------------------------------------
__global__ void prep_kernel(const float* __restrict__ W_fg, const float* __restrict__ b_fg,
                            const float* __restrict__ W_go, const float* __restrict__ b_go,
                            const float* __restrict__ W_out,
                            unsigned short* __restrict__ Wc, float* __restrict__ bc,
                            unsigned short* __restrict__ Woutb) {
  int idx = blockIdx.x * 256 + threadIdx.x;
  if (idx < 640 * 128) {
    int rr = idx >> 7, k = idx & 127;
    float v, bv;
    if (rr < 512) {
      int m = rr >> 7;
      int srow = (m == 1) ? rr + 128 : (m == 2) ? rr - 128 : rr;
      v = W_fg[srow * 128 + k];
      bv = b_fg[srow];
    } else {
      int srow = rr - 512;
      v = W_go[srow * 128 + k];
      bv = b_go[srow];
    }
    Wc[idx] = f2bf(v);
    if (k == 0) bc[rr] = bv;
  } else {
    int i2 = idx - 640 * 128;
    if (i2 < 128 * 128) Woutb[i2] = f2bf(W_out[i2]);
  }
}

// ---------------------------------------------------------------------------
// K0: LayerNorm over last dim (128) of edges; write x as bf16. 1 wave = 1 row.
// ---------------------------------------------------------------------------
__global__ __launch_bounds__(256) void ln1_kernel(const float* __restrict__ edges,
                                                  const float* __restrict__ w,
                                                  const float* __restrict__ b,
                                                  unsigned short* __restrict__ xb) {
  int wv = threadIdx.x >> 6;
  int lane = threadIdx.x & 63;
  size_t row = (size_t)blockIdx.x * 4 + wv;
  const float2* e = (const float2*)(edges + row * 128);
  float2 v = e[lane];
  float s = v.x + v.y, sq = v.x * v.x + v.y * v.y;
#pragma unroll
  for (int off = 32; off; off >>= 1) {
    s += __shfl_xor(s, off);
    sq += __shfl_xor(sq, off);
  }
  float mu = s * (1.f / 128.f);
  float var = sq * (1.f / 128.f) - mu * mu;
  float rs = rsqrtf(var + 1e-5f);
  int c = lane * 2;
  float x0 = (v.x - mu) * rs * w[c] + b[c];
  float x1 = (v.y - mu) * rs * w[c + 1] + b[c + 1];
  unsigned int packed = (unsigned int)f2bf(x0) | ((unsigned int)f2bf(x1) << 16);
  ((unsigned int*)(xb + row * 128))[lane] = packed;
}

// ---------------------------------------------------------------------------
// K1a: fg GEMM + gating + mask. Block: 64 rows x 256 cols (128 feat + 128
// gate), K=128. blockIdx.y: 0 -> to (Wc rows 0..255), 1 -> from (256..511).
// Writes transposed (channel-major) bf16: dst[c*RTOT + r].
// ---------------------------------------------------------------------------
__global__ __launch_bounds__(256) void fg_gemm_kernel(
    const unsigned short* __restrict__ xb, const unsigned short* __restrict__ Wc,
    const float* __restrict__ bc, const int* __restrict__ mask,
    unsigned short* __restrict__ toT, unsigned short* __restrict__ fromT) {
  int nb = blockIdx.y;
  int wv = threadIdx.x >> 6, lane = threadIdx.x & 63;
  int qm = lane & 15, quad = lane >> 4;
  int rw = blockIdx.x * 64 + wv * 16;
  int nbase = nb * 256;

  f32x4 acc[16];
#pragma unroll
  for (int t = 0; t < 16; t++) acc[t] = (f32x4){0.f, 0.f, 0.f, 0.f};

#pragma unroll
  for (int kk = 0; kk < 4; kk++) {
    int ko = kk * 32 + quad * 8;
    bf16x8 a = *(const bf16x8*)(xb + (size_t)(rw + qm) * 128 + ko);
#pragma unroll
    for (int t = 0; t < 16; t++) {
      bf16x8 bf = *(const bf16x8*)(Wc + (size_t)(nbase + t * 16 + qm) * 128 + ko);
      acc[t] = __builtin_amdgcn_mfma_f32_16x16x32_bf16(a, bf, acc[t], 0, 0, 0);
    }
  }

  int rbase = rw + quad * 4;
  int4 mi = *(const int4*)(mask + rbase);
  float mk[4] = {mi.x ? 1.f : 0.f, mi.y ? 1.f : 0.f, mi.z ? 1.f : 0.f, mi.w ? 1.f : 0.f};
  unsigned short* dst = (nb == 0) ? toT : fromT;
#pragma unroll
  for (int t = 0; t < 8; t++) {
    int c = t * 16 + qm;
    float bF = bc[nbase + c];
    float bG = bc[nbase + 128 + c];
    ushort4 pk;
    float v0 = (acc[t][0] + bF) * sigmoidf(acc[t + 8][0] + bG) * mk[0];
    float v1 = (acc[t][1] + bF) * sigmoidf(acc[t + 8][1] + bG) * mk[1];
    float v2 = (acc[t][2] + bF) * sigmoidf(acc[t + 8][2] + bG) * mk[2];
    float v3 = (acc[t][3] + bF) * sigmoidf(acc[t + 8][3] + bG) * mk[3];
    pk.x = f2bf(v0); pk.y = f2bf(v1); pk.z = f2bf(v2); pk.w = f2bf(v3);
    *(ushort4*)(dst + (size_t)c * RTOT + rbase) = pk;
  }
}

// ---------------------------------------------------------------------------
// K1b: out_gate = sigmoid(x @ W_go^T + b_go) * mask, fp32, natural (r, c)
// layout, written into d_out (re-read and overwritten by K3).
// ---------------------------------------------------------------------------
__global__ __launch_bounds__(256) void go_gemm_kernel(
    const unsigned short* __restrict__ xb, const unsigned short* __restrict__ Wc,
    const float* __restrict__ bc, const int* __restrict__ mask,
    float* __restrict__ gate_out) {
  int wv = threadIdx.x >> 6, lane = threadIdx.x & 63;
  int qm = lane & 15, quad = lane >> 4;
  int rw = blockIdx.x * 64 + wv * 16;

  f32x4 acc[8];
#pragma unroll
  for (int t = 0; t < 8; t++) acc[t] = (f32x4){0.f, 0.f, 0.f, 0.f};

#pragma unroll
  for (int kk = 0; kk < 4; kk++) {
    int ko = kk * 32 + quad * 8;
    bf16x8 a = *(const bf16x8*)(xb + (size_t)(rw + qm) * 128 + ko);
#pragma unroll
    for (int t = 0; t < 8; t++) {
      bf16x8 bf = *(const bf16x8*)(Wc + (size_t)(512 + t * 16 + qm) * 128 + ko);
      acc[t] = __builtin_amdgcn_mfma_f32_16x16x32_bf16(a, bf, acc[t], 0, 0, 0);
    }
  }

  int rbase = rw + quad * 4;
  int4 mi = *(const int4*)(mask + rbase);
  float mk[4] = {mi.x ? 1.f : 0.f, mi.y ? 1.f : 0.f, mi.z ? 1.f : 0.f, mi.w ? 1.f : 0.f};
#pragma unroll
  for (int t = 0; t < 8; t++) {
    int c = t * 16 + qm;
    float bG = bc[512 + c];
#pragma unroll
    for (int reg = 0; reg < 4; reg++) {
      float g = sigmoidf(acc[t][reg] + bG) * mk[reg];
      gate_out[(size_t)(rbase + reg) * 128 + c] = g;
    }
  }
}

// ---------------------------------------------------------------------------
// K2: tri[d] = To_d (512x512) @ From_d^T (512x512), 128 batched NT GEMMs.
// Block: 64x64 tile, K=512. Operands channel-major (d, r) -> both k-contig.
// ---------------------------------------------------------------------------
__global__ __launch_bounds__(256) void tri_gemm_kernel(
    const unsigned short* __restrict__ toT, const unsigned short* __restrict__ fromT,
    unsigned short* __restrict__ triT) {
  int d = blockIdx.z;
  int i0 = blockIdx.x * 64, j0 = blockIdx.y * 64;
  int wv = threadIdx.x >> 6, lane = threadIdx.x & 63;
  int qm = lane & 15, quad = lane >> 4;
  const unsigned short* A = toT + (size_t)d * RTOT;
  const unsigned short* B = fromT + (size_t)d * RTOT;
  int im = i0 + wv * 16 + qm;

  f32x4 acc[4];
#pragma unroll
  for (int t = 0; t < 4; t++) acc[t] = (f32x4){0.f, 0.f, 0.f, 0.f};

#pragma unroll 4
  for (int kk = 0; kk < 16; kk++) {
    int ko = kk * 32 + quad * 8;
    bf16x8 a = *(const bf16x8*)(A + (size_t)im * 512 + ko);
#pragma unroll
    for (int t = 0; t < 4; t++) {
      bf16x8 bf = *(const bf16x8*)(B + (size_t)(j0 + t * 16 + qm) * 512 + ko);
      acc[t] = __builtin_amdgcn_mfma_f32_16x16x32_bf16(a, bf, acc[t], 0, 0, 0);
    }
  }

  unsigned short* C = triT + (size_t)d * RTOT;
  int ib = i0 + wv * 16 + quad * 4;
#pragma unroll
  for (int t = 0; t < 4; t++) {
    int j = j0 + t * 16 + qm;
#pragma unroll
    for (int reg = 0; reg < 4; reg++) C[(size_t)(ib + reg) * 512 + j] = f2bf(acc[t][reg]);
  }
}

// ---------------------------------------------------------------------------
// K3: per-row LN2 over d=128 of tri, then @ W_out^T + b_out, * gate (in-place
// in d_out). Block: 64 rows. triT is channel-major -> LDS transpose stage.
// ---------------------------------------------------------------------------
__global__ __launch_bounds__(256) void out_kernel(
    const unsigned short* __restrict__ triT, const unsigned short* __restrict__ Woutb,
    const float* __restrict__ ln2w, const float* __restrict__ ln2b,
    const float* __restrict__ b_out, float* __restrict__ out) {
  __shared__ unsigned short nt[64][136]; // +8 pad breaks bank conflicts, keeps 16B align
  int r0 = blockIdx.x * 64;
  int tid = threadIdx.x;

  { // stage: thread -> (channel d, half-row range), transpose into LDS
    int dch = tid >> 1, rh = (tid & 1) * 32;
    const unsigned short* src = triT + (size_t)dch * RTOT + r0 + rh;
#pragma unroll 8
    for (int u = 0; u < 32; u++) nt[rh + u][dch] = src[u];
  }
  __syncthreads();

  int wv = tid >> 6, lane = tid & 63;
  int qm = lane & 15, quad = lane >> 4;

  { // LN stats + in-place normalize: 4 lanes per position, 32 channels each
    int p = wv * 16 + (lane >> 2), part = lane & 3;
    float s = 0.f, sq = 0.f;
#pragma unroll 8
    for (int u = 0; u < 32; u++) {
      float v = bf2f(nt[p][part * 32 + u]);
      s += v; sq += v * v;
    }
    s += __shfl_xor(s, 1); sq += __shfl_xor(sq, 1);
    s += __shfl_xor(s, 2); sq += __shfl_xor(sq, 2);
    float mu = s * (1.f / 128.f);
    float var = sq * (1.f / 128.f) - mu * mu;
    float rs = rsqrtf(var + 1e-5f);
#pragma unroll 8
    for (int u = 0; u < 32; u++) {
      int hc = part * 32 + u;
      float v = bf2f(nt[p][hc]);
      nt[p][hc] = f2bf((v - mu) * rs * ln2w[hc] + ln2b[hc]);
    }
  }
  __syncthreads();

  f32x4 acc[8];
#pragma unroll
  for (int t = 0; t < 8; t++) acc[t] = (f32x4){0.f, 0.f, 0.f, 0.f};
#pragma unroll
  for (int kk = 0; kk < 4; kk++) {
    int ko = kk * 32 + quad * 8;
    bf16x8 a = *(const bf16x8*)(&nt[wv * 16 + qm][ko]);
#pragma unroll
    for (int t = 0; t < 8; t++) {
      bf16x8 bf = *(const bf16x8*)(Woutb + (size_t)(t * 16 + qm) * 128 + ko);
      acc[t] = __builtin_amdgcn_mfma_f32_16x16x32_bf16(a, bf, acc[t], 0, 0, 0);
    }
  }

  int rbase = r0 + wv * 16 + quad * 4;
#pragma unroll
  for (int t = 0; t < 8; t++) {
    int c = t * 16 + qm;
    float bo = b_out[c];
#pragma unroll
    for (int reg = 0; reg < 4; reg++) {
      size_t off = (size_t)(rbase + reg) * 128 + c;
      out[off] = (acc[t][reg] + bo) * out[off]; // out[] currently holds gate
    }
  }
}

// ---------------------------------------------------------------------------
extern "C" void kernel_launch(void* const* d_in, const int* in_sizes, int n_in,
                              void* d_out, int out_size, void* d_ws, size_t ws_size,
                              hipStream_t stream) {
  const float* edges = (const float*)d_in[0];
  const int* mask = (const int*)d_in[1];
  const float* ln1w = (const float*)d_in[2];
  const float* ln1b = (const float*)d_in[3];
  const float* W_fg = (const float*)d_in[4];
  const float* b_fg = (const float*)d_in[5];
  const float* W_go = (const float*)d_in[6];
  const float* b_go = (const float*)d_in[7];
  const float* ln2w = (const float*)d_in[8];
  const float* ln2b = (const float*)d_in[9];
  const float* W_out = (const float*)d_in[10];
  const float* b_out = (const float*)d_in[11];

  char* ws = (char*)d_ws;
  const size_t SZ = (size_t)RTOT * DCH * 2; // 67,108,864 B per bf16 buffer
  unsigned short* xb = (unsigned short*)ws;
  unsigned short* toT = (unsigned short*)(ws + SZ);
  unsigned short* fromT = (unsigned short*)(ws + 2 * SZ);
  unsigned short* Wc = (unsigned short*)(ws + 3 * SZ);
  float* bc = (float*)(ws + 3 * SZ + 640 * 128 * 2);
  unsigned short* Woutb = (unsigned short*)(ws + 3 * SZ + 640 * 128 * 2 + 640 * 4);
  unsigned short* triT = xb; // xb dead after K1 -> reuse
  float* gate = (float*)d_out;

  prep_kernel<<<384, 256, 0, stream>>>(W_fg, b_fg, W_go, b_go, W_out, Wc, bc, Woutb);
  ln1_kernel<<<RTOT / 4, 256, 0, stream>>>(edges, ln1w, ln1b, xb);
  fg_gemm_kernel<<<dim3(RTOT / 64, 2), 256, 0, stream>>>(xb, Wc, bc, mask, toT, fromT);
  go_gemm_kernel<<<RTOT / 64, 256, 0, stream>>>(xb, Wc, bc, mask, gate);
  tri_gemm_kernel<<<dim3(8, 8, 128), 256, 0, stream>>>(toT, fromT, triT);
  out_kernel<<<RTOT / 64, 256, 0, stream>>>(triT, Woutb, ln2w, ln2b, b_out, gate);
}

// Round 3
// 839.338 us; speedup vs baseline: 1.2727x; 1.2727x over previous
//
#include <hip/hip_runtime.h>

#define NSEQ 512
#define DCH 128
#define RTOT (NSEQ * NSEQ) /* 262144 */

typedef __attribute__((ext_vector_type(8))) short bf16x8;
typedef __attribute__((ext_vector_type(4))) float f32x4;

__device__ __forceinline__ unsigned short f2bf(float v) {
  union { float f; unsigned int u; } x; x.f = v;
  unsigned int u = x.u;
  return (unsigned short)((u + 0x7fffu + ((u >> 16) & 1u)) >> 16);
}
__device__ __forceinline__ float bf2f(unsigned short s) {
  union { unsigned int u; float f; } x; x.u = ((unsigned int)s) << 16;
  return x.f;
}
__device__ __forceinline__ float sigmoidf(float x) { return 1.f / (1.f + __expf(-x)); }

// async global->LDS, 16B per lane; LDS dst is wave-uniform base (+ lane*16 implicit)
__device__ __forceinline__ void async16(const unsigned short* g, unsigned short* l) {
  __builtin_amdgcn_global_load_lds(
      (const __attribute__((address_space(1))) unsigned int*)g,
      (__attribute__((address_space(3))) unsigned int*)l, 16, 0, 0);
}

// ---------------------------------------------------------------------------
// prep: pack weights (reordered) into bf16.  Wc rows: [0,128)=to-feat,
// [128,256)=to-gate, [256,384)=from-feat, [384,512)=from-gate, [512,640)=go.
// ---------------------------------------------------------------------------
__global__ void prep_kernel(const float* __restrict__ W_fg, const float* __restrict__ b_fg,
                            const float* __restrict__ W_go, const float* __restrict__ b_go,
                            const float* __restrict__ W_out,
                            unsigned short* __restrict__ Wc, float* __restrict__ bc,
                            unsigned short* __restrict__ Woutb) {
  int idx = blockIdx.x * 256 + threadIdx.x;
  if (idx < 640 * 128) {
    int rr = idx >> 7, k = idx & 127;
    float v, bv;
    if (rr < 512) {
      int m = rr >> 7;
      int srow = (m == 1) ? rr + 128 : (m == 2) ? rr - 128 : rr;
      v = W_fg[srow * 128 + k];
      bv = b_fg[srow];
    } else {
      int srow = rr - 512;
      v = W_go[srow * 128 + k];
      bv = b_go[srow];
    }
    Wc[idx] = f2bf(v);
    if (k == 0) bc[rr] = bv;
  } else {
    int i2 = idx - 640 * 128;
    if (i2 < 128 * 128) Woutb[i2] = f2bf(W_out[i2]);
  }
}

// ---------------------------------------------------------------------------
// K0: LayerNorm over last dim (128) of edges; write x as bf16. 1 wave = 1 row.
// ---------------------------------------------------------------------------
__global__ __launch_bounds__(256) void ln1_kernel(const float* __restrict__ edges,
                                                  const float* __restrict__ w,
                                                  const float* __restrict__ b,
                                                  unsigned short* __restrict__ xb) {
  int wv = threadIdx.x >> 6;
  int lane = threadIdx.x & 63;
  size_t row = (size_t)blockIdx.x * 4 + wv;
  const float2* e = (const float2*)(edges + row * 128);
  float2 v = e[lane];
  float s = v.x + v.y, sq = v.x * v.x + v.y * v.y;
#pragma unroll
  for (int off = 32; off; off >>= 1) {
    s += __shfl_xor(s, off);
    sq += __shfl_xor(sq, off);
  }
  float mu = s * (1.f / 128.f);
  float var = sq * (1.f / 128.f) - mu * mu;
  float rs = rsqrtf(var + 1e-5f);
  int c = lane * 2;
  float x0 = (v.x - mu) * rs * w[c] + b[c];
  float x1 = (v.y - mu) * rs * w[c + 1] + b[c + 1];
  unsigned int packed = (unsigned int)f2bf(x0) | ((unsigned int)f2bf(x1) << 16);
  ((unsigned int*)(xb + row * 128))[lane] = packed;
}

// ---------------------------------------------------------------------------
// K1a: fg GEMM + gating + mask. Block: 64 rows x 256 cols, K=128.
// blockIdx.y: 0 -> to, 1 -> from. Writes channel-major bf16 dst[c*RTOT + r].
// ---------------------------------------------------------------------------
__global__ __launch_bounds__(256) void fg_gemm_kernel(
    const unsigned short* __restrict__ xb, const unsigned short* __restrict__ Wc,
    const float* __restrict__ bc, const int* __restrict__ mask,
    unsigned short* __restrict__ toT, unsigned short* __restrict__ fromT) {
  int nb = blockIdx.y;
  int wv = threadIdx.x >> 6, lane = threadIdx.x & 63;
  int qm = lane & 15, quad = lane >> 4;
  int rw = blockIdx.x * 64 + wv * 16;
  int nbase = nb * 256;

  f32x4 acc[16];
#pragma unroll
  for (int t = 0; t < 16; t++) acc[t] = (f32x4){0.f, 0.f, 0.f, 0.f};

#pragma unroll
  for (int kk = 0; kk < 4; kk++) {
    int ko = kk * 32 + quad * 8;
    bf16x8 a = *(const bf16x8*)(xb + (size_t)(rw + qm) * 128 + ko);
#pragma unroll
    for (int t = 0; t < 16; t++) {
      bf16x8 bf = *(const bf16x8*)(Wc + (size_t)(nbase + t * 16 + qm) * 128 + ko);
      acc[t] = __builtin_amdgcn_mfma_f32_16x16x32_bf16(a, bf, acc[t], 0, 0, 0);
    }
  }

  int rbase = rw + quad * 4;
  int4 mi = *(const int4*)(mask + rbase);
  float mk[4] = {mi.x ? 1.f : 0.f, mi.y ? 1.f : 0.f, mi.z ? 1.f : 0.f, mi.w ? 1.f : 0.f};
  unsigned short* dst = (nb == 0) ? toT : fromT;
#pragma unroll
  for (int t = 0; t < 8; t++) {
    int c = t * 16 + qm;
    float bF = bc[nbase + c];
    float bG = bc[nbase + 128 + c];
    ushort4 pk;
    float v0 = (acc[t][0] + bF) * sigmoidf(acc[t + 8][0] + bG) * mk[0];
    float v1 = (acc[t][1] + bF) * sigmoidf(acc[t + 8][1] + bG) * mk[1];
    float v2 = (acc[t][2] + bF) * sigmoidf(acc[t + 8][2] + bG) * mk[2];
    float v3 = (acc[t][3] + bF) * sigmoidf(acc[t + 8][3] + bG) * mk[3];
    pk.x = f2bf(v0); pk.y = f2bf(v1); pk.z = f2bf(v2); pk.w = f2bf(v3);
    *(ushort4*)(dst + (size_t)c * RTOT + rbase) = pk;
  }
}

// ---------------------------------------------------------------------------
// K1b: out_gate = sigmoid(x @ W_go^T + b_go) * mask, fp32, into d_out.
// ---------------------------------------------------------------------------
__global__ __launch_bounds__(256) void go_gemm_kernel(
    const unsigned short* __restrict__ xb, const unsigned short* __restrict__ Wc,
    const float* __restrict__ bc, const int* __restrict__ mask,
    float* __restrict__ gate_out) {
  int wv = threadIdx.x >> 6, lane = threadIdx.x & 63;
  int qm = lane & 15, quad = lane >> 4;
  int rw = blockIdx.x * 64 + wv * 16;

  f32x4 acc[8];
#pragma unroll
  for (int t = 0; t < 8; t++) acc[t] = (f32x4){0.f, 0.f, 0.f, 0.f};

#pragma unroll
  for (int kk = 0; kk < 4; kk++) {
    int ko = kk * 32 + quad * 8;
    bf16x8 a = *(const bf16x8*)(xb + (size_t)(rw + qm) * 128 + ko);
#pragma unroll
    for (int t = 0; t < 8; t++) {
      bf16x8 bf = *(const bf16x8*)(Wc + (size_t)(512 + t * 16 + qm) * 128 + ko);
      acc[t] = __builtin_amdgcn_mfma_f32_16x16x32_bf16(a, bf, acc[t], 0, 0, 0);
    }
  }

  int rbase = rw + quad * 4;
  int4 mi = *(const int4*)(mask + rbase);
  float mk[4] = {mi.x ? 1.f : 0.f, mi.y ? 1.f : 0.f, mi.z ? 1.f : 0.f, mi.w ? 1.f : 0.f};
#pragma unroll
  for (int t = 0; t < 8; t++) {
    int c = t * 16 + qm;
    float bG = bc[512 + c];
#pragma unroll
    for (int reg = 0; reg < 4; reg++) {
      float g = sigmoidf(acc[t][reg] + bG) * mk[reg];
      gate_out[(size_t)(rbase + reg) * 128 + c] = g;
    }
  }
}

// ---------------------------------------------------------------------------
// K2: tri[d] = To_d (512x512) @ From_d^T, 128 batched NT GEMMs.
// 128x128 tile/block, BK=64, global_load_lds(16B) staging, 4 waves x (4x4)
// MFMA accs. Epilogue repacks C through padded LDS -> dwordx4 stores.
// ---------------------------------------------------------------------------
__global__ __launch_bounds__(256) void tri_gemm_kernel(
    const unsigned short* __restrict__ toT, const unsigned short* __restrict__ fromT,
    unsigned short* __restrict__ triT) {
  __shared__ unsigned short smem[128 * 136]; // K-loop: As=[0,8192) Bs=[8192,16384); epilogue: C 128x136
  unsigned short* As = smem;
  unsigned short* Bs = smem + 128 * 64;

  int d = blockIdx.z;
  int i0 = blockIdx.x * 128, j0 = blockIdx.y * 128;
  int tid = threadIdx.x, w = tid >> 6, lane = tid & 63;
  int qm = lane & 15, quad = lane >> 4;
  int wm = w >> 1, wn = w & 1;
  const unsigned short* A = toT + (size_t)d * RTOT;
  const unsigned short* B = fromT + (size_t)d * RTOT;
  int lr = lane >> 3, lk = (lane & 7) * 8;

  f32x4 acc[4][4];
#pragma unroll
  for (int m = 0; m < 4; m++)
#pragma unroll
    for (int n = 0; n < 4; n++) acc[m][n] = (f32x4){0.f, 0.f, 0.f, 0.f};

  for (int kb = 0; kb < 512; kb += 64) {
    __syncthreads(); // prev compute done reading LDS
#pragma unroll
    for (int q = 0; q < 4; q++) {
      int blk = w * 4 + q; // 16 row-blocks of 8 rows each
      async16(A + (size_t)(i0 + blk * 8 + lr) * 512 + kb + lk, As + blk * 512);
      async16(B + (size_t)(j0 + blk * 8 + lr) * 512 + kb + lk, Bs + blk * 512);
    }
    __syncthreads(); // loads drained (compiler emits vmcnt(0) before barrier)
#pragma unroll
    for (int kk = 0; kk < 2; kk++) {
      bf16x8 af[4], bfr[4];
#pragma unroll
      for (int m = 0; m < 4; m++)
        af[m] = *(const bf16x8*)(As + (wm * 64 + m * 16 + qm) * 64 + kk * 32 + quad * 8);
#pragma unroll
      for (int n = 0; n < 4; n++)
        bfr[n] = *(const bf16x8*)(Bs + (wn * 64 + n * 16 + qm) * 64 + kk * 32 + quad * 8);
#pragma unroll
      for (int m = 0; m < 4; m++)
#pragma unroll
        for (int n = 0; n < 4; n++)
          acc[m][n] = __builtin_amdgcn_mfma_f32_16x16x32_bf16(af[m], bfr[n], acc[m][n], 0, 0, 0);
    }
  }

  __syncthreads(); // done with As/Bs; reuse smem as C 128x136 (pad keeps 16B align, kills conflicts)
#pragma unroll
  for (int m = 0; m < 4; m++) {
    int rb = wm * 64 + m * 16 + quad * 4;
#pragma unroll
    for (int n = 0; n < 4; n++) {
      int col = wn * 64 + n * 16 + qm;
#pragma unroll
      for (int reg = 0; reg < 4; reg++)
        smem[(rb + reg) * 136 + col] = f2bf(acc[m][n][reg]);
    }
  }
  __syncthreads();
  { // each (row, half) copies its FULL 64-short half: 8 x uint4 (r2 bug: was 4)
    int row = tid >> 1, half = tid & 1;
    const uint4* src = (const uint4*)(smem + row * 136 + half * 64);
    uint4 v[8];
#pragma unroll
    for (int u = 0; u < 8; u++) v[u] = src[u];
    uint4* dst = (uint4*)(triT + (size_t)d * RTOT + (size_t)(i0 + row) * 512 + j0 + half * 64);
#pragma unroll
    for (int u = 0; u < 8; u++) dst[u] = v[u];
  }
}

// ---------------------------------------------------------------------------
// K3: LN2 over d=128 of tri (channel-major input), @ W_out^T + b_out, * gate.
// Vectorized staging; LN fused into MFMA A-fragment build.
// ---------------------------------------------------------------------------
__global__ __launch_bounds__(256) void out_kernel(
    const unsigned short* __restrict__ triT, const unsigned short* __restrict__ Woutb,
    const float* __restrict__ ln2w, const float* __restrict__ ln2b,
    const float* __restrict__ b_out, float* __restrict__ out) {
  __shared__ unsigned short nt[64][136];
  __shared__ float mu_s[64], rs_s[64];
  int r0 = blockIdx.x * 64;
  int tid = threadIdx.x;

  { // stage 64 rows x 128 ch, transposing channel-major -> row-major
    int dch = tid >> 1, half = tid & 1;
    const uint4* src = (const uint4*)(triT + (size_t)dch * RTOT + r0 + half * 32);
    uint4 v[4];
    v[0] = src[0]; v[1] = src[1]; v[2] = src[2]; v[3] = src[3];
    const unsigned short* pv = (const unsigned short*)v;
#pragma unroll
    for (int u = 0; u < 32; u++) nt[half * 32 + u][dch] = pv[u];
  }
  __syncthreads();

  { // LN2 stats: 4 lanes per position
    int p = tid >> 2, part = tid & 3;
    float s = 0.f, sq = 0.f;
#pragma unroll
    for (int u = 0; u < 4; u++) {
      bf16x8 v = *(const bf16x8*)(&nt[p][part * 32 + u * 8]);
#pragma unroll
      for (int e = 0; e < 8; e++) {
        float f = bf2f((unsigned short)v[e]);
        s += f; sq += f * f;
      }
    }
    s += __shfl_xor(s, 1); sq += __shfl_xor(sq, 1);
    s += __shfl_xor(s, 2); sq += __shfl_xor(sq, 2);
    float mu = s * (1.f / 128.f);
    float var = sq * (1.f / 128.f) - mu * mu;
    if (part == 0) { mu_s[p] = mu; rs_s[p] = rsqrtf(var + 1e-5f); }
  }
  __syncthreads();

  int wv = tid >> 6, lane = tid & 63;
  int qm = lane & 15, quad = lane >> 4;
  int p = wv * 16 + qm;
  float mu = mu_s[p], rs = rs_s[p];

  bf16x8 afr[4];
#pragma unroll
  for (int kk = 0; kk < 4; kk++) { // build normalized A-fragments (elementwise: no aliased cast)
    int ko = kk * 32 + quad * 8;
    bf16x8 raw = *(const bf16x8*)(&nt[p][ko]);
#pragma unroll
    for (int e = 0; e < 8; e++) {
      float wf = ln2w[ko + e], bv = ln2b[ko + e];
      afr[kk][e] = (short)f2bf((bf2f((unsigned short)raw[e]) - mu) * rs * wf + bv);
    }
  }

  f32x4 acc[8];
#pragma unroll
  for (int t = 0; t < 8; t++) acc[t] = (f32x4){0.f, 0.f, 0.f, 0.f};
#pragma unroll
  for (int kk = 0; kk < 4; kk++) {
    int ko = kk * 32 + quad * 8;
#pragma unroll
    for (int t = 0; t < 8; t++) {
      bf16x8 bf = *(const bf16x8*)(Woutb + (size_t)(t * 16 + qm) * 128 + ko);
      acc[t] = __builtin_amdgcn_mfma_f32_16x16x32_bf16(afr[kk], bf, acc[t], 0, 0, 0);
    }
  }

  int rbase = r0 + wv * 16 + quad * 4;
#pragma unroll
  for (int t = 0; t < 8; t++) {
    int c = t * 16 + qm;
    float bo = b_out[c];
#pragma unroll
    for (int reg = 0; reg < 4; reg++) {
      size_t off = (size_t)(rbase + reg) * 128 + c;
      out[off] = (acc[t][reg] + bo) * out[off]; // out[] currently holds gate
    }
  }
}

// ---------------------------------------------------------------------------
extern "C" void kernel_launch(void* const* d_in, const int* in_sizes, int n_in,
                              void* d_out, int out_size, void* d_ws, size_t ws_size,
                              hipStream_t stream) {
  const float* edges = (const float*)d_in[0];
  const int* mask = (const int*)d_in[1];
  const float* ln1w = (const float*)d_in[2];
  const float* ln1b = (const float*)d_in[3];
  const float* W_fg = (const float*)d_in[4];
  const float* b_fg = (const float*)d_in[5];
  const float* W_go = (const float*)d_in[6];
  const float* b_go = (const float*)d_in[7];
  const float* ln2w = (const float*)d_in[8];
  const float* ln2b = (const float*)d_in[9];
  const float* W_out = (const float*)d_in[10];
  const float* b_out = (const float*)d_in[11];

  char* ws = (char*)d_ws;
  const size_t SZ = (size_t)RTOT * DCH * 2; // 64 MiB per bf16 buffer
  unsigned short* xb = (unsigned short*)ws;
  unsigned short* toT = (unsigned short*)(ws + SZ);
  unsigned short* fromT = (unsigned short*)(ws + 2 * SZ);
  unsigned short* Wc = (unsigned short*)(ws + 3 * SZ);
  float* bc = (float*)(ws + 3 * SZ + 640 * 128 * 2);
  unsigned short* Woutb = (unsigned short*)(ws + 3 * SZ + 640 * 128 * 2 + 640 * 4);
  unsigned short* triT = xb; // xb dead after K1 -> reuse
  float* gate = (float*)d_out;

  prep_kernel<<<384, 256, 0, stream>>>(W_fg, b_fg, W_go, b_go, W_out, Wc, bc, Woutb);
  ln1_kernel<<<RTOT / 4, 256, 0, stream>>>(edges, ln1w, ln1b, xb);
  fg_gemm_kernel<<<dim3(RTOT / 64, 2), 256, 0, stream>>>(xb, Wc, bc, mask, toT, fromT);
  go_gemm_kernel<<<RTOT / 64, 256, 0, stream>>>(xb, Wc, bc, mask, gate);
  tri_gemm_kernel<<<dim3(4, 4, 128), 256, 0, stream>>>(toT, fromT, triT);
  out_kernel<<<RTOT / 64, 256, 0, stream>>>(triT, Woutb, ln2w, ln2b, b_out, gate);
}